// Round 17
// baseline (213.497 us; speedup 1.0000x reference)
//
#include <hip/hip_runtime.h>
#include <math.h>

#define BATCH 1024
#define BITS  2048

typedef __attribute__((ext_vector_type(8))) short bf16x8;
typedef __attribute__((ext_vector_type(4))) float f32x4;
typedef _Float16 f16_t;
typedef __attribute__((ext_vector_type(8))) _Float16 f16x8;

__device__ __constant__ double D_PI = 3.141592653589793;

static __device__ __forceinline__ unsigned short f32_to_bf16(float f) {
    unsigned int u = __float_as_uint(f);
    u += 0x7fffu + ((u >> 16) & 1u);
    return (unsigned short)(u >> 16);
}

// async global->LDS, 16B per lane; LDS dest wave-uniform base + lane*16
static __device__ __forceinline__ void glds16(const void* g, void* l) {
    __builtin_amdgcn_global_load_lds(
        (const __attribute__((address_space(1))) unsigned int*)g,
        (__attribute__((address_space(3))) unsigned int*)l, 16, 0, 0);
}

// XCD-aware swizzle for 512-block 32x16 tilings [r9-validated] (cost kernel).
static __device__ __forceinline__ void tile_map(int i, int& row0, int& col0) {
    const int xcd = i & 7, j = i >> 3;
    const int rl = j & 7, cl = j >> 3;
    row0 = (((xcd & 1) * 8) + rl) * 64;
    col0 = (((xcd >> 1) * 8) + cl) * 64;
}

// ---------------------------------------------------------------------------
// Prep (5121 blocks) [r12-validated]:
//   [0,2048)    : W -> Eh, El limb planes (E = W - I exact in f32)
//   [2048,3072) : x -> xh, xl limb planes
//   [3072,5120) : Q (f32) -> Qb (bf16, same layout; streamed convert)
//   5120        : zero out[1024]
// ---------------------------------------------------------------------------
__global__ __launch_bounds__(256)
void prep_kernel(const float* __restrict__ W, const float* __restrict__ x,
                 const float* __restrict__ Q,
                 f16_t* __restrict__ eh, f16_t* __restrict__ el,
                 f16_t* __restrict__ xh, f16_t* __restrict__ xl,
                 unsigned short* __restrict__ Qb, float* __restrict__ out)
{
    const int b = blockIdx.x, t = threadIdx.x;
    if (b < 2048) {
        const size_t base = ((size_t)b * 256 + t) * 8;
        const int n  = (int)(base >> 11);
        const int k0 = (int)(base & 2047);
        float4 w0 = *(const float4*)&W[base];
        float4 w1 = *(const float4*)&W[base + 4];
        float wv[8] = {w0.x,w0.y,w0.z,w0.w,w1.x,w1.y,w1.z,w1.w};
        f16x8 hv, lv;
        #pragma unroll
        for (int j = 0; j < 8; ++j) {
            float e = wv[j] - ((n == k0 + j) ? 1.0f : 0.0f);
            f16_t h = (f16_t)e;
            hv[j] = h;
            lv[j] = (f16_t)((e - (float)h) * 2048.0f);
        }
        *(f16x8*)&eh[base] = hv;
        *(f16x8*)&el[base] = lv;
    } else if (b < 3072) {
        const size_t base = ((size_t)(b - 2048) * 256 + t) * 8;
        float4 v0 = *(const float4*)&x[base];
        float4 v1 = *(const float4*)&x[base + 4];
        float vv[8] = {v0.x,v0.y,v0.z,v0.w,v1.x,v1.y,v1.z,v1.w};
        f16x8 hv, lv;
        #pragma unroll
        for (int j = 0; j < 8; ++j) {
            f16_t h = (f16_t)vv[j];
            hv[j] = h;
            lv[j] = (f16_t)((vv[j] - (float)h) * 2048.0f);
        }
        *(f16x8*)&xh[base] = hv;
        *(f16x8*)&xl[base] = lv;
    } else if (b < 5120) {
        const size_t base = ((size_t)(b - 3072) * 256 + t) * 8;
        float4 q0 = *(const float4*)&Q[base];
        float4 q1 = *(const float4*)&Q[base + 4];
        float qv[8] = {q0.x,q0.y,q0.z,q0.w,q1.x,q1.y,q1.z,q1.w};
        bf16x8 bv;
        #pragma unroll
        for (int j = 0; j < 8; ++j) bv[j] = (short)f32_to_bf16(qv[j]);
        *(bf16x8*)&Qb[base] = bv;
    } else {
        *(float4*)&out[t * 4] = (float4){0.f, 0.f, 0.f, 0.f};
    }
}

// ---------------------------------------------------------------------------
// Layer, r19: OCCUPANCY. 1024 blocks x 256 threads, block tile 32x64,
// wave tile 16x32 (2x2 waves), BK=64, single-buffer 24KB LDS ->
// 4 blocks/CU resident = 16 waves/CU (was 8 in r4/r16/r18).
// [r4/r16/r18 post-mortem: three different schedules (1-phase, 2-phase
// dbuf, 3-buffer counted-vmcnt) ALL land at 45-47us, MfmaUtil ~20%,
// Occupancy ~19% -> schedule-invariant stall = latency-bound at
// 2 waves/SIMD. m93 (2 blk/CU) = 20.7% of peak, m97 (~4 blk/CU) = 35%:
// occupancy is the lever, cross-block overlap the mechanism (m114).]
// 1-phase loop (r14-proven): stage -> sync -> compute -> sync; 4
// resident blocks alternate staging/compute phases. Proven pieces:
// r16 XOR swizzle (row owns 128B line, slot (kb^(r&7))<<4 — r17's
// conflict lesson), glds16, fold at (it&7)==7 (k mult 512), f64
// epilogue. Per-output K-sum order identical to r16/r18 -> bit-same.
// LDS buf: xh [0,4K) | xl [4K,8K) | Eh [8K,16K) | El [16K,24K).
// mode 0: h as f16 limb pair.  mode 1: xb = (noise < h) ? bf16(1) : 0.
// ---------------------------------------------------------------------------
__global__ __launch_bounds__(256, 4)
void layer_mfma(const f16_t* __restrict__ Ah, const f16_t* __restrict__ Al,
                const f16_t* __restrict__ Ehp, const f16_t* __restrict__ Elp,
                const float* __restrict__ directF,
                const f16_t* __restrict__ dH, const f16_t* __restrict__ dL,
                const float* __restrict__ bias, const float* __restrict__ noise,
                f16_t* __restrict__ h_hi, f16_t* __restrict__ h_lo,
                unsigned short* __restrict__ xb_out, int mode)
{
    __shared__ __align__(16) char smem[24576];

    const int t = threadIdx.x;
    const int wvi = t >> 6, lane = t & 63;
    const int quad = lane >> 4, li = lane & 15;
    const int mw = wvi & 1, nw = wvi >> 1;        // 2x2 wave grid
    // 1024 blocks: bijective XCD swizzle (1024%8==0); 32(M) x 32(N) tiles.
    const int wg = (blockIdx.x & 7) * 128 + (blockIdx.x >> 3);
    const int row0 = (wg & 31) * 32;
    const int col0 = (wg >> 5) * 64;

    f32x4 a1[2], a2[2], tot[2];                   // [tn]
    #pragma unroll
    for (int tn = 0; tn < 2; ++tn) {
        a1[tn]  = (f32x4){0.f,0.f,0.f,0.f};
        a2[tn]  = (f32x4){0.f,0.f,0.f,0.f};
        tot[tn] = (f32x4){0.f,0.f,0.f,0.f};
    }
    const float C1 = 1.0f / 2048.0f;

    // stage-side decode (constant per thread): chunk c -> row c>>3,
    // k-chunk k8 = (c&7)^(row&7) (r16-proven, conflict-free on read).
    const int rx  = t >> 3,          kx  = (t & 7) ^ (rx & 7);          // x planes: c = t
    const int re0 = t >> 3,          ke0 = (t & 7) ^ (re0 & 7);         // E chunk c = t
    const int re1 = (256 + t) >> 3,  ke1 = ((256 + t) & 7) ^ (re1 & 7); // E chunk c = 256+t

    auto stage = [&](int itn) {
        const int k0s = itn * 64;
        glds16(&Ah [(size_t)(row0 + rx)  * BITS + k0s + kx  * 8], smem + t * 16);
        glds16(&Al [(size_t)(row0 + rx)  * BITS + k0s + kx  * 8], smem + 4096 + t * 16);
        glds16(&Ehp[(size_t)(col0 + re0) * BITS + k0s + ke0 * 8], smem + 8192 + t * 16);
        glds16(&Ehp[(size_t)(col0 + re1) * BITS + k0s + ke1 * 8], smem + 8192 + (256 + t) * 16);
        glds16(&Elp[(size_t)(col0 + re0) * BITS + k0s + ke0 * 8], smem + 16384 + t * 16);
        glds16(&Elp[(size_t)(col0 + re1) * BITS + k0s + ke1 * 8], smem + 16384 + (256 + t) * 16);
    };

    for (int it = 0; it < 32; ++it) {
        stage(it);
        __syncthreads();

        #pragma unroll
        for (int ks = 0; ks < 2; ++ks) {
            const int kb = ks * 4 + quad;   // k-chunk 0..7 within the window
            f16x8 fxh, fxl, feh[2], fel[2];
            {
                const int r = mw * 16 + li;
                const int s = (r * 8 + (kb ^ (r & 7))) * 16;
                fxh = *(const f16x8*)(smem + s);
                fxl = *(const f16x8*)(smem + 4096 + s);
            }
            #pragma unroll
            for (int tn = 0; tn < 2; ++tn) {
                const int r = nw * 32 + tn * 16 + li;
                const int s = (r * 8 + (kb ^ (r & 7))) * 16;
                feh[tn] = *(const f16x8*)(smem + 8192 + s);
                fel[tn] = *(const f16x8*)(smem + 16384 + s);
            }
            __builtin_amdgcn_s_setprio(1);
            #pragma unroll
            for (int tn = 0; tn < 2; ++tn) {
                a1[tn] = __builtin_amdgcn_mfma_f32_16x16x32_f16(fxh, feh[tn], a1[tn], 0, 0, 0);
                a2[tn] = __builtin_amdgcn_mfma_f32_16x16x32_f16(fxl, feh[tn], a2[tn], 0, 0, 0);
                a2[tn] = __builtin_amdgcn_mfma_f32_16x16x32_f16(fxh, fel[tn], a2[tn], 0, 0, 0);
            }
            __builtin_amdgcn_s_setprio(0);
        }

        if ((it & 7) == 7) {   // global k multiple of 512 (r5/r12 numerics)
            #pragma unroll
            for (int tn = 0; tn < 2; ++tn) {
                tot[tn] = tot[tn] + (a1[tn] + C1 * a2[tn]);
                a1[tn] = (f32x4){0.f,0.f,0.f,0.f};
                a2[tn] = (f32x4){0.f,0.f,0.f,0.f};
            }
        }
        __syncthreads();
    }

    #pragma unroll
    for (int tn = 0; tn < 2; ++tn)
        #pragma unroll
        for (int r = 0; r < 4; ++r) {
            const int m = row0 + mw * 16 + quad * 4 + r;
            const int n = col0 + nw * 32 + tn * 16 + li;
            const size_t idx = (size_t)m * BITS + n;
            double direct;
            if (mode == 0) {
                direct = (double)directF[idx];
            } else {
                direct = (double)(float)dH[idx]
                       + (double)(float)dL[idx] * (1.0 / 2048.0);
            }
            double pre = (double)tot[tn][r] + direct + (double)bias[n];
            double h = 0.5 * (1.0 + sin((pre - 0.5) * D_PI));
            if (mode == 0) {
                f16_t hh = (f16_t)h;
                h_hi[idx] = hh;
                h_lo[idx] = (f16_t)((h - (double)(float)hh) * 2048.0);
            } else {
                xb_out[idx] = ((double)noise[idx] < h) ? (unsigned short)0x3F80
                                                       : (unsigned short)0;
            }
        }
}

// ---------------------------------------------------------------------------
// Cost [r16-proven: 0 bank conflicts]: BK=64, 2-buffer dbuf, glds16 + XOR
// swizzle (slot (c&7)^(row&7)), 2 bufs x (2 planes x 8KB) = 32KB, 2
// blocks/CU. out[b] = sum_i u[b][i]*xb[b][i], u = xb @ Qb rows.
// (Retile for occupancy next round if r19's layer result confirms.)
// ---------------------------------------------------------------------------
__global__ __launch_bounds__(256, 2)
void cost_kernel(const unsigned short* __restrict__ xb,
                 const unsigned short* __restrict__ Qb,
                 float* __restrict__ out)
{
    __shared__ __align__(16) char smem[32768];
    __shared__ float red[2][64][17];

    const int t = threadIdx.x;
    const int wvi = t >> 6, lane = t & 63;
    const int quad = lane >> 4, li = lane & 15;
    const int mw = wvi & 1, nw = wvi >> 1;
    int b0, i0;
    tile_map(blockIdx.x, b0, i0);

    f32x4 acc[2][2];
    #pragma unroll
    for (int tm = 0; tm < 2; ++tm)
        #pragma unroll
        for (int tn = 0; tn < 2; ++tn)
            acc[tm][tn] = (f32x4){0.f, 0.f, 0.f, 0.f};

    auto stage = [&](int itn, int buf) {
        const int k0s = itn * 64;
        #pragma unroll
        for (int issue = 0; issue < 4; ++issue) {
            const int chunk = issue * 256 + wvi * 64 + lane;
            const int c   = chunk & 511;
            const int row = c >> 3;
            const int k8  = (c & 7) ^ (row & 7);
            const unsigned short* plane = (issue < 2) ? xb : Qb;
            const int rbase = (issue < 2) ? b0 : i0;
            glds16(&plane[(size_t)(rbase + row) * BITS + k0s + k8 * 8],
                   smem + buf * 16384 + (issue * 256 + wvi * 64) * 16);
        }
    };

    int cur = 0;
    stage(0, 0);
    __syncthreads();

    for (int it = 0; it < 32; ++it) {
        if (it + 1 < 32) stage(it + 1, cur ^ 1);

        const char* sb = smem + cur * 16384;
        #pragma unroll
        for (int ks = 0; ks < 2; ++ks) {
            const int kb = ks * 4 + quad;
            bf16x8 af[2], bfr[2];
            #pragma unroll
            for (int tm = 0; tm < 2; ++tm) {
                const int r = mw * 32 + tm * 16 + li;
                const int s = (r * 8 + (kb ^ (r & 7))) * 16;
                af[tm] = *(const bf16x8*)(sb + s);
            }
            #pragma unroll
            for (int tn = 0; tn < 2; ++tn) {
                const int r = nw * 32 + tn * 16 + li;
                const int s = (r * 8 + (kb ^ (r & 7))) * 16;
                bfr[tn] = *(const bf16x8*)(sb + 8192 + s);
            }
            __builtin_amdgcn_s_setprio(1);
            #pragma unroll
            for (int tm = 0; tm < 2; ++tm)
                #pragma unroll
                for (int tn = 0; tn < 2; ++tn)
                    acc[tm][tn] = __builtin_amdgcn_mfma_f32_16x16x32_bf16(
                        af[tm], bfr[tn], acc[tm][tn], 0, 0, 0);
            __builtin_amdgcn_s_setprio(0);
        }
        __syncthreads();
        cur ^= 1;
    }

    #pragma unroll
    for (int tm = 0; tm < 2; ++tm) {
        #pragma unroll
        for (int r = 0; r < 4; ++r) {
            const int bl = mw * 32 + tm * 16 + quad * 4 + r;
            const int bg = b0 + bl;
            float p = 0.f;
            #pragma unroll
            for (int tn = 0; tn < 2; ++tn) {
                const int ig = i0 + nw * 32 + tn * 16 + li;
                if (xb[(size_t)bg * BITS + ig]) p += acc[tm][tn][r];
            }
            red[nw][bl][li] = p;
        }
    }
    __syncthreads();
    if (t < 64) {
        float s = 0.f;
        #pragma unroll
        for (int c = 0; c < 16; ++c) s += red[0][t][c] + red[1][t][c];
        atomicAdd(&out[b0 + t], s);
    }
}

// ---------------------------------------------------------------------------
extern "C" void kernel_launch(void* const* d_in, const int* in_sizes, int n_in,
                              void* d_out, int out_size, void* d_ws, size_t ws_size,
                              hipStream_t stream)
{
    const float* x     = (const float*)d_in[0];
    const float* noise = (const float*)d_in[1];
    const float* W1    = (const float*)d_in[2];
    const float* b1    = (const float*)d_in[3];
    const float* b2    = (const float*)d_in[5];   // == b1 by construction
    const float* Q     = (const float*)d_in[6];
    float* out = (float*)d_out;

    // ws: xh xl | Eh El | h1h h1l | Qb = 41.9 MB; xb aliases xh (dead after L1)
    char* w = (char*)d_ws;
    const size_t SZX = (size_t)BATCH * BITS * 2;
    const size_t SZW = (size_t)BITS * BITS * 2;
    f16_t* xh  = (f16_t*)(w);
    f16_t* xl  = (f16_t*)(w + SZX);
    f16_t* eh  = (f16_t*)(w + 2 * SZX);
    f16_t* el  = (f16_t*)(w + 2 * SZX + SZW);
    f16_t* h1h = (f16_t*)(w + 2 * SZX + 2 * SZW);
    f16_t* h1l = (f16_t*)(w + 3 * SZX + 2 * SZW);
    unsigned short* Qb = (unsigned short*)(w + 4 * SZX + 2 * SZW);
    unsigned short* xb = (unsigned short*)(w);   // alias xh: dead after L1

    prep_kernel<<<5121, 256, 0, stream>>>(W1, x, Q, eh, el, xh, xl, Qb, out);
    layer_mfma<<<1024, 256, 0, stream>>>(xh, xl, eh, el, x, nullptr, nullptr,
                                         b1, nullptr, h1h, h1l, nullptr, 0);
    layer_mfma<<<1024, 256, 0, stream>>>(h1h, h1l, eh, el, nullptr, h1h, h1l,
                                         b2, noise, nullptr, nullptr, xb, 1);
    cost_kernel<<<512, 256, 0, stream>>>(xb, Qb, out);
}

// Round 22
// 204.118 us; speedup vs baseline: 1.0459x; 1.0459x over previous
//
#include <hip/hip_runtime.h>
#include <math.h>

#define BATCH 1024
#define BITS  2048

typedef __attribute__((ext_vector_type(8))) short bf16x8;
typedef __attribute__((ext_vector_type(4))) float f32x4;
typedef _Float16 f16_t;
typedef __attribute__((ext_vector_type(8))) _Float16 f16x8;

__device__ __constant__ double D_PI = 3.141592653589793;

static __device__ __forceinline__ unsigned short f32_to_bf16(float f) {
    unsigned int u = __float_as_uint(f);
    u += 0x7fffu + ((u >> 16) & 1u);
    return (unsigned short)(u >> 16);
}

// async global->LDS, 16B per lane; LDS dest wave-uniform base + lane*16
static __device__ __forceinline__ void glds16(const void* g, void* l) {
    __builtin_amdgcn_global_load_lds(
        (const __attribute__((address_space(1))) unsigned int*)g,
        (__attribute__((address_space(3))) unsigned int*)l, 16, 0, 0);
}

// XCD-aware swizzle for 512-block 32x16 tilings [r9-validated] (cost kernel).
static __device__ __forceinline__ void tile_map(int i, int& row0, int& col0) {
    const int xcd = i & 7, j = i >> 3;
    const int rl = j & 7, cl = j >> 3;
    row0 = (((xcd & 1) * 8) + rl) * 64;
    col0 = (((xcd >> 1) * 8) + cl) * 64;
}

// ---------------------------------------------------------------------------
// Prep (5121 blocks) [r12-validated]:
//   [0,2048)    : W -> Eh, El limb planes (E = W - I exact in f32)
//   [2048,3072) : x -> xh, xl limb planes
//   [3072,5120) : Q (f32) -> Qb (bf16, same layout; streamed convert)
//   5120        : zero out[1024]
// ---------------------------------------------------------------------------
__global__ __launch_bounds__(256)
void prep_kernel(const float* __restrict__ W, const float* __restrict__ x,
                 const float* __restrict__ Q,
                 f16_t* __restrict__ eh, f16_t* __restrict__ el,
                 f16_t* __restrict__ xh, f16_t* __restrict__ xl,
                 unsigned short* __restrict__ Qb, float* __restrict__ out)
{
    const int b = blockIdx.x, t = threadIdx.x;
    if (b < 2048) {
        const size_t base = ((size_t)b * 256 + t) * 8;
        const int n  = (int)(base >> 11);
        const int k0 = (int)(base & 2047);
        float4 w0 = *(const float4*)&W[base];
        float4 w1 = *(const float4*)&W[base + 4];
        float wv[8] = {w0.x,w0.y,w0.z,w0.w,w1.x,w1.y,w1.z,w1.w};
        f16x8 hv, lv;
        #pragma unroll
        for (int j = 0; j < 8; ++j) {
            float e = wv[j] - ((n == k0 + j) ? 1.0f : 0.0f);
            f16_t h = (f16_t)e;
            hv[j] = h;
            lv[j] = (f16_t)((e - (float)h) * 2048.0f);
        }
        *(f16x8*)&eh[base] = hv;
        *(f16x8*)&el[base] = lv;
    } else if (b < 3072) {
        const size_t base = ((size_t)(b - 2048) * 256 + t) * 8;
        float4 v0 = *(const float4*)&x[base];
        float4 v1 = *(const float4*)&x[base + 4];
        float vv[8] = {v0.x,v0.y,v0.z,v0.w,v1.x,v1.y,v1.z,v1.w};
        f16x8 hv, lv;
        #pragma unroll
        for (int j = 0; j < 8; ++j) {
            f16_t h = (f16_t)vv[j];
            hv[j] = h;
            lv[j] = (f16_t)((vv[j] - (float)h) * 2048.0f);
        }
        *(f16x8*)&xh[base] = hv;
        *(f16x8*)&xl[base] = lv;
    } else if (b < 5120) {
        const size_t base = ((size_t)(b - 3072) * 256 + t) * 8;
        float4 q0 = *(const float4*)&Q[base];
        float4 q1 = *(const float4*)&Q[base + 4];
        float qv[8] = {q0.x,q0.y,q0.z,q0.w,q1.x,q1.y,q1.z,q1.w};
        bf16x8 bv;
        #pragma unroll
        for (int j = 0; j < 8; ++j) bv[j] = (short)f32_to_bf16(qv[j]);
        *(bf16x8*)&Qb[base] = bv;
    } else {
        *(float4*)&out[t * 4] = (float4){0.f, 0.f, 0.f, 0.f};
    }
}

// ---------------------------------------------------------------------------
// Layer, r18 [MEASURED BEST, round 9: total 203.9us, layers 46.6us —
// byte-identical here]: 64x128 tile, 512 threads (8 waves), BK=64,
// 3-BUFFER COUNTED-VMCNT pipeline, 144KB LDS.
// [r19 REFUTED occupancy: 4 blk/CU of 32x64 tiles = 53us. Additive model
// (fits r16/r18/r19): T = staged*(1/128+1/56) + reads/128 + MFMA; smaller
// tiles raise traffic/FLOP faster than residency pays. M=1024 caps tile
// area at 2 blk/CU -> r16/r18 are the structural optimum (~45-47us).]
// Stage = 6 glds16/wave/tile. Steady: s_waitcnt vmcnt(6); s_barrier;
// stage(t+2); compute(t) — tile t+1 in flight across barrier (T4).
// Proven-conflict-free layout: row owns 128B line, slot (kb^(r&7))<<4.
// Numerics: same MFMA order, fold a1 + 2^-11*a2 at (tt&7)==7, f64 epi.
// mode 0: h as f16 limb pair.  mode 1: xb = (noise < h) ? bf16(1) : 0.
// ---------------------------------------------------------------------------
__global__ __launch_bounds__(512, 1)
void layer_mfma(const f16_t* __restrict__ Ah, const f16_t* __restrict__ Al,
                const f16_t* __restrict__ Ehp, const f16_t* __restrict__ Elp,
                const float* __restrict__ directF,
                const f16_t* __restrict__ dH, const f16_t* __restrict__ dL,
                const float* __restrict__ bias, const float* __restrict__ noise,
                f16_t* __restrict__ h_hi, f16_t* __restrict__ h_lo,
                unsigned short* __restrict__ xb_out, int mode)
{
    __shared__ __align__(16) char smem[147456];   // 3 bufs x 48KB

    const int t = threadIdx.x;
    const int wvi = t >> 6, lane = t & 63;
    const int quad = lane >> 4, li = lane & 15;
    const int mw = wvi & 1, nw = wvi >> 1;        // nw 0..3
    // 256 blocks: bijective XCD swizzle (256%8==0), 16x16 tile grid.
    const int wg = (blockIdx.x & 7) * 32 + (blockIdx.x >> 3);
    const int row0 = (wg & 15) * 64;
    const int col0 = (wg >> 4) * 128;

    // stage-side decode: chunk ca in [0,512) per 8KB plane-half.
    const int ca = wvi * 64 + lane;
    const int rowa = ca >> 3;
    const int k8a = (ca & 7) ^ (rowa & 7);

    f32x4 a1[2][2], a2[2][2], tot[2][2];
    #pragma unroll
    for (int tm = 0; tm < 2; ++tm)
        #pragma unroll
        for (int tn = 0; tn < 2; ++tn) {
            a1[tm][tn]  = (f32x4){0.f,0.f,0.f,0.f};
            a2[tm][tn]  = (f32x4){0.f,0.f,0.f,0.f};
            tot[tm][tn] = (f32x4){0.f,0.f,0.f,0.f};
        }
    const float C1 = 1.0f / 2048.0f;

    // stage one BK=64 tile (48KB) into buffer `buf`: 6 glds16 per wave.
    auto stage = [&](int itn, int buf) {
        const int k0s = itn * 64 + k8a * 8;
        char* B = smem + buf * 49152 + wvi * 1024;
        glds16(&Ah [(size_t)(row0 + rowa)      * BITS + k0s], B);
        glds16(&Al [(size_t)(row0 + rowa)      * BITS + k0s], B + 8192);
        glds16(&Ehp[(size_t)(col0 + rowa)      * BITS + k0s], B + 16384);
        glds16(&Ehp[(size_t)(col0 + 64 + rowa) * BITS + k0s], B + 24576);
        glds16(&Elp[(size_t)(col0 + rowa)      * BITS + k0s], B + 32768);
        glds16(&Elp[(size_t)(col0 + 64 + rowa) * BITS + k0s], B + 40960);
    };

    stage(0, 0); stage(1, 1);   // 12 loads in flight

    int tt = 0, cbuf = 0, sbuf = 2;
    #define LAYER_COMPUTE()                                                       \
    {                                                                             \
        const char* sbp = smem + cbuf * 49152;                                    \
        _Pragma("unroll")                                                         \
        for (int ks = 0; ks < 2; ++ks) {                                          \
            const int kb = ks * 4 + quad;                                         \
            f16x8 fxh[2], fxl[2], feh[2], fel[2];                                 \
            _Pragma("unroll")                                                     \
            for (int tm = 0; tm < 2; ++tm) {                                      \
                const int r = mw * 32 + tm * 16 + li;                             \
                const int s = (r * 8 + (kb ^ (r & 7))) * 16;                      \
                fxh[tm] = *(const f16x8*)(sbp + s);                               \
                fxl[tm] = *(const f16x8*)(sbp + 8192 + s);                        \
            }                                                                     \
            _Pragma("unroll")                                                     \
            for (int tn = 0; tn < 2; ++tn) {                                      \
                const int r = nw * 32 + tn * 16 + li;                             \
                const int s = (r * 8 + (kb ^ (r & 7))) * 16;                      \
                feh[tn] = *(const f16x8*)(sbp + 16384 + s);                       \
                fel[tn] = *(const f16x8*)(sbp + 32768 + s);                       \
            }                                                                     \
            __builtin_amdgcn_s_setprio(1);                                        \
            _Pragma("unroll")                                                     \
            for (int tm = 0; tm < 2; ++tm)                                        \
                _Pragma("unroll")                                                 \
                for (int tn = 0; tn < 2; ++tn) {                                  \
                    a1[tm][tn] = __builtin_amdgcn_mfma_f32_16x16x32_f16(fxh[tm], feh[tn], a1[tm][tn], 0, 0, 0); \
                    a2[tm][tn] = __builtin_amdgcn_mfma_f32_16x16x32_f16(fxl[tm], feh[tn], a2[tm][tn], 0, 0, 0); \
                    a2[tm][tn] = __builtin_amdgcn_mfma_f32_16x16x32_f16(fxh[tm], fel[tn], a2[tm][tn], 0, 0, 0); \
                }                                                                 \
            __builtin_amdgcn_s_setprio(0);                                        \
        }                                                                         \
        if ((tt & 7) == 7) {                                                      \
            _Pragma("unroll")                                                     \
            for (int tm = 0; tm < 2; ++tm)                                        \
                _Pragma("unroll")                                                 \
                for (int tn = 0; tn < 2; ++tn) {                                  \
                    tot[tm][tn] = tot[tm][tn] + (a1[tm][tn] + C1 * a2[tm][tn]);   \
                    a1[tm][tn] = (f32x4){0.f,0.f,0.f,0.f};                        \
                    a2[tm][tn] = (f32x4){0.f,0.f,0.f,0.f};                        \
                }                                                                 \
        }                                                                         \
    }

    for (; tt < 30; ++tt) {
        asm volatile("s_waitcnt vmcnt(6)\n\ts_barrier" ::: "memory");
        stage(tt + 2, sbuf);
        sbuf = (sbuf == 2) ? 0 : sbuf + 1;
        LAYER_COMPUTE();
        cbuf = (cbuf == 2) ? 0 : cbuf + 1;
    }
    asm volatile("s_waitcnt vmcnt(6)\n\ts_barrier" ::: "memory");
    LAYER_COMPUTE();                                   // tt == 30
    cbuf = (cbuf == 2) ? 0 : cbuf + 1; ++tt;
    asm volatile("s_waitcnt vmcnt(0)\n\ts_barrier" ::: "memory");
    LAYER_COMPUTE();                                   // tt == 31 (final fold)
    #undef LAYER_COMPUTE

    #pragma unroll
    for (int tm = 0; tm < 2; ++tm)
        #pragma unroll
        for (int tn = 0; tn < 2; ++tn)
            #pragma unroll
            for (int r = 0; r < 4; ++r) {
                const int m = row0 + mw * 32 + tm * 16 + quad * 4 + r;
                const int n = col0 + nw * 32 + tn * 16 + li;
                const size_t idx = (size_t)m * BITS + n;
                double direct;
                if (mode == 0) {
                    direct = (double)directF[idx];
                } else {
                    direct = (double)(float)dH[idx]
                           + (double)(float)dL[idx] * (1.0 / 2048.0);
                }
                double pre = (double)tot[tm][tn][r] + direct + (double)bias[n];
                double h = 0.5 * (1.0 + sin((pre - 0.5) * D_PI));
                if (mode == 0) {
                    f16_t hh = (f16_t)h;
                    h_hi[idx] = hh;
                    h_lo[idx] = (f16_t)((h - (double)(float)hh) * 2048.0);
                } else {
                    xb_out[idx] = ((double)noise[idx] < h) ? (unsigned short)0x3F80
                                                           : (unsigned short)0;
                }
            }
}

// ---------------------------------------------------------------------------
// Cost, r20: 3-BUFFER COUNTED-VMCNT (inherits the layer template verified
// round 9; r16's 2-buffer loop degenerates to a vmcnt(0) drain per its own
// post-mortem). Stage = 4 glds16/lane/tile; prologue stages tiles 0,1
// (8 outstanding); steady: vmcnt(4) -> tile t landed, t+1 in flight;
// barrier; stage(t+2, (t+2)%3); compute(t). Tail vmcnt(4)/vmcnt(0).
// Compute order unchanged -> bit-identical numerics. LDS 3x16KB + red =
// 56.7KB -> 2 blocks/CU kept. Swizzle: r16-proven (c&7)^(row&7).
// out[b] = sum_i u[b][i]*xb[b][i], u = xb @ Qb rows.
// ---------------------------------------------------------------------------
__global__ __launch_bounds__(256, 2)
void cost_kernel(const unsigned short* __restrict__ xb,
                 const unsigned short* __restrict__ Qb,
                 float* __restrict__ out)
{
    __shared__ __align__(16) char smem[49152];   // 3 bufs x 16KB
    __shared__ float red[2][64][17];

    const int t = threadIdx.x;
    const int wvi = t >> 6, lane = t & 63;
    const int quad = lane >> 4, li = lane & 15;
    const int mw = wvi & 1, nw = wvi >> 1;
    int b0, i0;
    tile_map(blockIdx.x, b0, i0);

    f32x4 acc[2][2];
    #pragma unroll
    for (int tm = 0; tm < 2; ++tm)
        #pragma unroll
        for (int tn = 0; tn < 2; ++tn)
            acc[tm][tn] = (f32x4){0.f, 0.f, 0.f, 0.f};

    auto stage = [&](int itn, int buf) {
        const int k0s = itn * 64;
        #pragma unroll
        for (int issue = 0; issue < 4; ++issue) {
            const int chunk = issue * 256 + wvi * 64 + lane;
            const int c   = chunk & 511;
            const int row = c >> 3;
            const int k8  = (c & 7) ^ (row & 7);
            const unsigned short* plane = (issue < 2) ? xb : Qb;
            const int rbase = (issue < 2) ? b0 : i0;
            glds16(&plane[(size_t)(rbase + row) * BITS + k0s + k8 * 8],
                   smem + buf * 16384 + (issue * 256 + wvi * 64) * 16);
        }
    };

    stage(0, 0); stage(1, 1);   // 8 loads in flight

    int tt = 0, cbuf = 0, sbuf = 2;
    #define COST_COMPUTE()                                                        \
    {                                                                             \
        const char* sb = smem + cbuf * 16384;                                     \
        _Pragma("unroll")                                                         \
        for (int ks = 0; ks < 2; ++ks) {                                          \
            const int kb = ks * 4 + quad;                                         \
            bf16x8 af[2], bfr[2];                                                 \
            _Pragma("unroll")                                                     \
            for (int tm = 0; tm < 2; ++tm) {                                      \
                const int r = mw * 32 + tm * 16 + li;                             \
                const int s = (r * 8 + (kb ^ (r & 7))) * 16;                      \
                af[tm] = *(const bf16x8*)(sb + s);                                \
            }                                                                     \
            _Pragma("unroll")                                                     \
            for (int tn = 0; tn < 2; ++tn) {                                      \
                const int r = nw * 32 + tn * 16 + li;                             \
                const int s = (r * 8 + (kb ^ (r & 7))) * 16;                      \
                bfr[tn] = *(const bf16x8*)(sb + 8192 + s);                        \
            }                                                                     \
            __builtin_amdgcn_s_setprio(1);                                        \
            _Pragma("unroll")                                                     \
            for (int tm = 0; tm < 2; ++tm)                                        \
                _Pragma("unroll")                                                 \
                for (int tn = 0; tn < 2; ++tn)                                    \
                    acc[tm][tn] = __builtin_amdgcn_mfma_f32_16x16x32_bf16(        \
                        af[tm], bfr[tn], acc[tm][tn], 0, 0, 0);                   \
            __builtin_amdgcn_s_setprio(0);                                        \
        }                                                                         \
    }

    for (; tt < 30; ++tt) {
        asm volatile("s_waitcnt vmcnt(4)\n\ts_barrier" ::: "memory");
        stage(tt + 2, sbuf);
        sbuf = (sbuf == 2) ? 0 : sbuf + 1;
        COST_COMPUTE();
        cbuf = (cbuf == 2) ? 0 : cbuf + 1;
    }
    asm volatile("s_waitcnt vmcnt(4)\n\ts_barrier" ::: "memory");
    COST_COMPUTE();                                    // tt == 30
    cbuf = (cbuf == 2) ? 0 : cbuf + 1; ++tt;
    asm volatile("s_waitcnt vmcnt(0)\n\ts_barrier" ::: "memory");
    COST_COMPUTE();                                    // tt == 31
    #undef COST_COMPUTE

    #pragma unroll
    for (int tm = 0; tm < 2; ++tm) {
        #pragma unroll
        for (int r = 0; r < 4; ++r) {
            const int bl = mw * 32 + tm * 16 + quad * 4 + r;
            const int bg = b0 + bl;
            float p = 0.f;
            #pragma unroll
            for (int tn = 0; tn < 2; ++tn) {
                const int ig = i0 + nw * 32 + tn * 16 + li;
                if (xb[(size_t)bg * BITS + ig]) p += acc[tm][tn][r];
            }
            red[nw][bl][li] = p;
        }
    }
    __syncthreads();
    if (t < 64) {
        float s = 0.f;
        #pragma unroll
        for (int c = 0; c < 16; ++c) s += red[0][t][c] + red[1][t][c];
        atomicAdd(&out[b0 + t], s);
    }
}

// ---------------------------------------------------------------------------
extern "C" void kernel_launch(void* const* d_in, const int* in_sizes, int n_in,
                              void* d_out, int out_size, void* d_ws, size_t ws_size,
                              hipStream_t stream)
{
    const float* x     = (const float*)d_in[0];
    const float* noise = (const float*)d_in[1];
    const float* W1    = (const float*)d_in[2];
    const float* b1    = (const float*)d_in[3];
    const float* b2    = (const float*)d_in[5];   // == b1 by construction
    const float* Q     = (const float*)d_in[6];
    float* out = (float*)d_out;

    // ws: xh xl | Eh El | h1h h1l | Qb = 41.9 MB; xb aliases xh (dead after L1)
    char* w = (char*)d_ws;
    const size_t SZX = (size_t)BATCH * BITS * 2;
    const size_t SZW = (size_t)BITS * BITS * 2;
    f16_t* xh  = (f16_t*)(w);
    f16_t* xl  = (f16_t*)(w + SZX);
    f16_t* eh  = (f16_t*)(w + 2 * SZX);
    f16_t* el  = (f16_t*)(w + 2 * SZX + SZW);
    f16_t* h1h = (f16_t*)(w + 2 * SZX + 2 * SZW);
    f16_t* h1l = (f16_t*)(w + 3 * SZX + 2 * SZW);
    unsigned short* Qb = (unsigned short*)(w + 4 * SZX + 2 * SZW);
    unsigned short* xb = (unsigned short*)(w);   // alias xh: dead after L1

    prep_kernel<<<5121, 256, 0, stream>>>(W1, x, Q, eh, el, xh, xl, Qb, out);
    layer_mfma<<<256, 512, 0, stream>>>(xh, xl, eh, el, x, nullptr, nullptr,
                                        b1, nullptr, h1h, h1l, nullptr, 0);
    layer_mfma<<<256, 512, 0, stream>>>(h1h, h1l, eh, el, nullptr, h1h, h1l,
                                        b2, noise, nullptr, nullptr, xb, 1);
    cost_kernel<<<512, 256, 0, stream>>>(xb, Qb, out);
}